// Round 4
// baseline (915.909 us; speedup 1.0000x reference)
//
#include <hip/hip_runtime.h>

namespace {

constexpr int NTH = 512;   // threads per block
constexpr int NB  = 512;   // GRU batch (original T)
constexpr int HID = 128;
constexpr int G3  = 384;
constexpr int SS  = 128;   // scan steps (original B)
constexpr int CH  = 20;    // padded LDS chunk stride for fallback kernel

typedef float    f32x2 __attribute__((ext_vector_type(2)));
typedef float    f32x4 __attribute__((ext_vector_type(4)));
typedef _Float16 f16;
typedef f16      f16x8 __attribute__((ext_vector_type(8)));

__device__ __forceinline__ void pk_fma_acc(f32x2& acc, f32x2 a, f32x2 b) {
    asm("v_pk_fma_f32 %0, %1, %2, %0" : "+v"(acc) : "v"(a), "v"(b));
}

template <int CTRL>
__device__ __forceinline__ float add_dpp(float v) {
    int moved = __builtin_amdgcn_update_dpp(0, __float_as_int(v), CTRL, 0xf, 0xf, true);
    return v + __int_as_float(moved);
}
__device__ __forceinline__ float wave_red8(float v) {
    v = add_dpp<0x111>(v);
    v = add_dpp<0x112>(v);
    v = add_dpp<0x114>(v);
    return v;
}

__device__ __forceinline__ float dot4acc(float4 a, float4 b, float acc) {
    acc = fmaf(a.x, b.x, acc);
    acc = fmaf(a.y, b.y, acc);
    acc = fmaf(a.z, b.z, acc);
    acc = fmaf(a.w, b.w, acc);
    return acc;
}

// sigmoid/tanh via hw exp; saturate correctly at +-inf without clamps
__device__ __forceinline__ float fsig(float x)  { return 1.f / (1.f + __expf(-x)); }
__device__ __forceinline__ float ftanh_(float x){ const float e = __expf(2.f * x); return 1.f - 2.f / (e + 1.f); }

__device__ __forceinline__ f16x8 zero8() {
    f16x8 z;
    #pragma unroll
    for (int e = 0; e < 8; ++e) z[e] = (f16)0.f;
    return z;
}

// ============================================================================
// Kernel 1: px GEMM (fp32).  px[m][g] = sum_k A[m][k]*W[g][k] + bih[g] + (g<256?bhh[g]:0)
// ============================================================================
constexpr int BKG = 32;
constexpr int TSTR = 132;

__global__ __launch_bounds__(256, 4) void px_gemm(
    const float* __restrict__ A, const float* __restrict__ W,
    const float* __restrict__ bih, const float* __restrict__ bhh,
    float* __restrict__ px, int kin)
{
    __shared__ __align__(16) float At[BKG * TSTR];
    __shared__ __align__(16) float Wt[BKG * TSTR];

    const int tid = threadIdx.x;
    const int m0  = blockIdx.x * 128;
    const int g0  = blockIdx.y * 128;
    const int tr  = tid >> 4;
    const int tc  = tid & 15;

    f32x2 acc2[8][4];
    #pragma unroll
    for (int i = 0; i < 8; ++i)
        #pragma unroll
        for (int j = 0; j < 4; ++j) acc2[i][j] = f32x2{0.f, 0.f};

    const int srow = tid >> 3;
    const int sf4  = (tid & 7) * 4;

    for (int kt = 0; kt < kin; kt += BKG) {
        #pragma unroll
        for (int p = 0; p < 4; ++p) {
            const int r = p * 32 + srow;
            const float4 va = *reinterpret_cast<const float4*>(A + (size_t)(m0 + r) * kin + kt + sf4);
            At[(sf4 + 0) * TSTR + r] = va.x;
            At[(sf4 + 1) * TSTR + r] = va.y;
            At[(sf4 + 2) * TSTR + r] = va.z;
            At[(sf4 + 3) * TSTR + r] = va.w;
            const float4 vw = *reinterpret_cast<const float4*>(W + (size_t)(g0 + r) * kin + kt + sf4);
            Wt[(sf4 + 0) * TSTR + r] = vw.x;
            Wt[(sf4 + 1) * TSTR + r] = vw.y;
            Wt[(sf4 + 2) * TSTR + r] = vw.z;
            Wt[(sf4 + 3) * TSTR + r] = vw.w;
        }
        __syncthreads();

        #pragma unroll 8
        for (int kk = 0; kk < BKG; ++kk) {
            const float4 a0 = *reinterpret_cast<const float4*>(&At[kk * TSTR + tr * 8]);
            const float4 a1 = *reinterpret_cast<const float4*>(&At[kk * TSTR + tr * 8 + 4]);
            const float4 w0 = *reinterpret_cast<const float4*>(&Wt[kk * TSTR + tc * 8]);
            const float4 w1 = *reinterpret_cast<const float4*>(&Wt[kk * TSTR + tc * 8 + 4]);
            const f32x2 wp[4] = { f32x2{w0.x, w0.y}, f32x2{w0.z, w0.w},
                                  f32x2{w1.x, w1.y}, f32x2{w1.z, w1.w} };
            const float ar[8] = { a0.x, a0.y, a0.z, a0.w, a1.x, a1.y, a1.z, a1.w };
            #pragma unroll
            for (int i = 0; i < 8; ++i) {
                const f32x2 av = f32x2{ar[i], ar[i]};
                #pragma unroll
                for (int j = 0; j < 4; ++j)
                    pk_fma_acc(acc2[i][j], av, wp[j]);
            }
        }
        __syncthreads();
    }

    const int gbase = g0 + tc * 8;
    const bool addz = (g0 < 256);
    float4 b0 = *reinterpret_cast<const float4*>(bih + gbase);
    float4 b1 = *reinterpret_cast<const float4*>(bih + gbase + 4);
    if (addz) {
        const float4 h0 = *reinterpret_cast<const float4*>(bhh + gbase);
        const float4 h1 = *reinterpret_cast<const float4*>(bhh + gbase + 4);
        b0.x += h0.x; b0.y += h0.y; b0.z += h0.z; b0.w += h0.w;
        b1.x += h1.x; b1.y += h1.y; b1.z += h1.z; b1.w += h1.w;
    }
    #pragma unroll
    for (int i = 0; i < 8; ++i) {
        const int m = m0 + tr * 8 + i;
        float4 o0, o1;
        o0.x = acc2[i][0].x + b0.x; o0.y = acc2[i][0].y + b0.y;
        o0.z = acc2[i][1].x + b0.z; o0.w = acc2[i][1].y + b0.w;
        o1.x = acc2[i][2].x + b1.x; o1.y = acc2[i][2].y + b1.y;
        o1.z = acc2[i][3].x + b1.z; o1.w = acc2[i][3].y + b1.w;
        *reinterpret_cast<float4*>(px + (size_t)m * G3 + gbase)     = o0;
        *reinterpret_cast<float4*>(px + (size_t)m * G3 + gbase + 4) = o1;
    }
}

// ============================================================================
// Kernel 2: MFMA recurrence. 32 blocks x 512 threads; 16 rows per block.
// Per step: gh = h @ w_hh.T via mfma_f32_16x16x32_f16, 3-pass hi/lo split.
// Wave w owns gate-column-tile w of r (tile w), z (tile w+8), n (tile w+16),
// so r/z/n for a column live in the same thread; h state stays fp32 in regs.
// h -> next-step A-frags goes through a 16KB double-buffered swizzled LDS tile.
// ============================================================================
__global__ __launch_bounds__(NTH) void gru_rec_mfma(
    const float* __restrict__ px,   // [SS*NB][384]  (biases folded: bih all, bhh for r,z)
    const float* __restrict__ whh,  // [384][128]
    const float* __restrict__ bhh,  // [384]
    float* __restrict__ yd)         // [SS][NB][HID]
{
    __shared__ _Float16 hlds[2][2][16 * HID];   // [dbuf][hi|lo][m*128+k], XOR-swizzled

    const int tid  = threadIdx.x;
    const int lane = tid & 63;
    const int w    = tid >> 6;      // wave 0..7 = gate-column tile
    const int l15  = lane & 15;
    const int q    = lane >> 4;     // lane quadrant 0..3
    const int colc = w * 16 + l15;  // hidden column owned (0..127)
    const int row0 = blockIdx.x * 16;

    // ---- stage W fragments (resident for all 128 steps) ----
    // B-frag for mfma_16x16x32: lane l holds B[(l>>4)*8+e][l&15] = whh[j0+l15][kt*32+q*8+e]
    f16x8 Whi[3][4], Wlo[3][4];
    #pragma unroll
    for (int g = 0; g < 3; ++g) {
        const int jrow = g * HID + colc;           // w_hh row = gate index
        #pragma unroll
        for (int kt = 0; kt < 4; ++kt) {
            const float* src = whh + (size_t)jrow * HID + kt * 32 + q * 8;
            const float4 a = *reinterpret_cast<const float4*>(src);
            const float4 b = *reinterpret_cast<const float4*>(src + 4);
            const float v[8] = {a.x, a.y, a.z, a.w, b.x, b.y, b.z, b.w};
            f16x8 hi, lo;
            #pragma unroll
            for (int e = 0; e < 8; ++e) {
                const f16 h = (f16)v[e];
                hi[e] = h;
                lo[e] = (f16)(v[e] - (float)h);
            }
            Whi[g][kt] = hi;
            Wlo[g][kt] = lo;
        }
    }
    const float bhn = bhh[256 + colc];

    float hstate[4] = {0.f, 0.f, 0.f, 0.f};
    f16x8 Ahi[4], Alo[4];
    #pragma unroll
    for (int kt = 0; kt < 4; ++kt) { Ahi[kt] = zero8(); Alo[kt] = zero8(); }  // h[0] = 0

    // px gather base: rows row0+4q+r, cols {colc, 128+colc, 256+colc}
    const float* pxbase = px + (size_t)(row0 + q * 4) * G3 + colc;
    float* ybase = yd + (size_t)(row0 + q * 4) * HID + colc;

    float pxc[12], pxn[12];
    #pragma unroll
    for (int g = 0; g < 3; ++g)
        #pragma unroll
        for (int r = 0; r < 4; ++r) {
            pxc[g * 4 + r] = pxbase[(size_t)r * G3 + g * HID];
            pxn[g * 4 + r] = pxbase[(size_t)NB * G3 + (size_t)r * G3 + g * HID];
        }

    for (int s = 0; s < SS; ++s) {
        // ---- gh = h @ w_hh.T : 36 MFMA, 3 independent 12-deep chains ----
        f32x4 accR = {0.f, 0.f, 0.f, 0.f};
        f32x4 accZ = {0.f, 0.f, 0.f, 0.f};
        f32x4 accN = {0.f, 0.f, 0.f, 0.f};
        #pragma unroll
        for (int kt = 0; kt < 4; ++kt) {
            accR = __builtin_amdgcn_mfma_f32_16x16x32_f16(Ahi[kt], Whi[0][kt], accR, 0, 0, 0);
            accZ = __builtin_amdgcn_mfma_f32_16x16x32_f16(Ahi[kt], Whi[1][kt], accZ, 0, 0, 0);
            accN = __builtin_amdgcn_mfma_f32_16x16x32_f16(Ahi[kt], Whi[2][kt], accN, 0, 0, 0);
        }
        #pragma unroll
        for (int kt = 0; kt < 4; ++kt) {
            accR = __builtin_amdgcn_mfma_f32_16x16x32_f16(Ahi[kt], Wlo[0][kt], accR, 0, 0, 0);
            accZ = __builtin_amdgcn_mfma_f32_16x16x32_f16(Ahi[kt], Wlo[1][kt], accZ, 0, 0, 0);
            accN = __builtin_amdgcn_mfma_f32_16x16x32_f16(Ahi[kt], Wlo[2][kt], accN, 0, 0, 0);
        }
        #pragma unroll
        for (int kt = 0; kt < 4; ++kt) {
            accR = __builtin_amdgcn_mfma_f32_16x16x32_f16(Alo[kt], Whi[0][kt], accR, 0, 0, 0);
            accZ = __builtin_amdgcn_mfma_f32_16x16x32_f16(Alo[kt], Whi[1][kt], accZ, 0, 0, 0);
            accN = __builtin_amdgcn_mfma_f32_16x16x32_f16(Alo[kt], Whi[2][kt], accN, 0, 0, 0);
        }

        // ---- gates (C-layout: row m=q*4+r, col=colc), y store, h->LDS f16 hi/lo ----
        _Float16* wb0 = &hlds[(s + 1) & 1][0][0];
        _Float16* wb1 = &hlds[(s + 1) & 1][1][0];
        #pragma unroll
        for (int r = 0; r < 4; ++r) {
            const float rr = fsig(pxc[r]     + accR[r]);
            const float zz = fsig(pxc[4 + r] + accZ[r]);
            const float nn = ftanh_(pxc[8 + r] + rr * (accN[r] + bhn));
            const float hn = (1.f - zz) * nn + zz * hstate[r];
            hstate[r] = hn;
            ybase[(size_t)s * NB * HID + (size_t)r * HID] = hn;
            const int m   = q * 4 + r;
            const int idx = (m * HID + colc) ^ ((m & 7) << 3);
            const f16 hh = (f16)hn;
            wb0[idx] = hh;
            wb1[idx] = (f16)(hn - (float)hh);
        }

        // ---- rotate px prefetch (2-deep) ----
        #pragma unroll
        for (int i = 0; i < 12; ++i) pxc[i] = pxn[i];
        if (s + 2 < SS) {
            const float* pb = pxbase + (size_t)(s + 2) * NB * G3;
            #pragma unroll
            for (int g = 0; g < 3; ++g)
                #pragma unroll
                for (int r = 0; r < 4; ++r)
                    pxn[g * 4 + r] = pb[(size_t)r * G3 + g * HID];
        }

        __syncthreads();

        // ---- A-frags for h[s+1]: lane l reads h[l15][kt*32+q*8 .. +7] ----
        const _Float16* rb0 = &hlds[(s + 1) & 1][0][0];
        const _Float16* rb1 = &hlds[(s + 1) & 1][1][0];
        #pragma unroll
        for (int kt = 0; kt < 4; ++kt) {
            const int idx = (l15 * HID + kt * 32 + q * 8) ^ ((l15 & 7) << 3);
            Ahi[kt] = *reinterpret_cast<const f16x8*>(rb0 + idx);
            Alo[kt] = *reinterpret_cast<const f16x8*>(rb1 + idx);
        }
    }
}

// ============================================================================
// Fallback: R1 fused kernel (used only if workspace is too small for px).
// ============================================================================
__global__ __launch_bounds__(NTH) void gru3_fused(
    const float* __restrict__ xin,
    const float* __restrict__ wih0, const float* __restrict__ whh0,
    const float* __restrict__ bih0, const float* __restrict__ bhh0,
    const float* __restrict__ wih1, const float* __restrict__ whh1,
    const float* __restrict__ bih1, const float* __restrict__ bhh1,
    const float* __restrict__ wih2, const float* __restrict__ whh2,
    const float* __restrict__ bih2, const float* __restrict__ bhh2,
    float* __restrict__ out)
{
    __shared__ __align__(16) float xb[2][2 * 8 * CH];
    __shared__ __align__(16) float hb[2 * 8 * CH];
    __shared__ float pxl[2][G3];
    __shared__ float ghl[2][G3];
    __shared__ float bsum[2 * HID];
    __shared__ float bin_[HID];
    __shared__ float bhn_[HID];

    const int tid  = threadIdx.x;
    const int kgrp = tid & 7;
    const int gt   = tid >> 3;
    const int g0   = gt * 6;
    const int row0 = blockIdx.x * 2;

    float4 wih[6][4];
    float4 whh[6][4];

    for (int layer = 0; layer < 3; ++layer) {
        const float *wi, *wh, *bi, *bh, *xs;
        float* yd;
        int kin;
        if (layer == 0)      { wi = wih0; wh = whh0; bi = bih0; bh = bhh0; xs = xin; yd = out; kin = 64;  }
        else if (layer == 1) { wi = wih1; wh = whh1; bi = bih1; bh = bhh1; xs = out; yd = out; kin = HID; }
        else                 { wi = wih2; wh = whh2; bi = bih2; bh = bhh2; xs = out; yd = out; kin = HID; }

        #pragma unroll
        for (int gg = 0; gg < 6; ++gg) {
            const int g = g0 + gg;
            #pragma unroll
            for (int q = 0; q < 4; ++q) {
                const int k = kgrp * 16 + q * 4;
                whh[gg][q] = *reinterpret_cast<const float4*>(wh + g * HID + k);
                if (k < kin)
                    wih[gg][q] = *reinterpret_cast<const float4*>(wi + g * kin + k);
                else
                    wih[gg][q] = make_float4(0.f, 0.f, 0.f, 0.f);
            }
        }

        for (int i = tid; i < 2 * HID; i += NTH) bsum[i] = bi[i] + bh[i];
        for (int i = tid; i < HID; i += NTH) { bin_[i] = bi[256 + i]; bhn_[i] = bh[256 + i]; }
        for (int i = tid; i < 2 * 8 * CH; i += NTH) { hb[i] = 0.f; xb[0][i] = 0.f; xb[1][i] = 0.f; }
        __syncthreads();
        if (tid < 256) {
            const int n = tid >> 7, j = tid & 127;
            if (j < kin)
                xb[0][n * (8 * CH) + (j >> 4) * CH + (j & 15)] = xs[(0 * NB + row0 + n) * kin + j];
        }
        __syncthreads();

        float ypend = 0.f;
        bool  have_y = false;

        for (int s = 0; s < SS; ++s) {
            float xpref = 0.f;
            if (tid >= 256) {
                const int t2 = tid - 256;
                const int n = t2 >> 7, j = t2 & 127;
                if (s + 1 < SS && j < kin)
                    xpref = xs[((s + 1) * NB + row0 + n) * kin + j];
            } else if (have_y) {
                const int n = tid >> 7, j = tid & 127;
                yd[((s - 1) * NB + row0 + n) * HID + j] = ypend;
            }

            float accp[2][6], accg[2][6];
            #pragma unroll
            for (int n = 0; n < 2; ++n)
                #pragma unroll
                for (int gg = 0; gg < 6; ++gg) { accp[n][gg] = 0.f; accg[n][gg] = 0.f; }

            const float* xcur = xb[s & 1];
            #pragma unroll
            for (int q = 0; q < 4; ++q) {
                const int off = kgrp * CH + q * 4;
                const float4 x0 = *reinterpret_cast<const float4*>(xcur + off);
                const float4 x1 = *reinterpret_cast<const float4*>(xcur + 8 * CH + off);
                const float4 h0 = *reinterpret_cast<const float4*>(hb + off);
                const float4 h1 = *reinterpret_cast<const float4*>(hb + 8 * CH + off);
                #pragma unroll
                for (int gg = 0; gg < 6; ++gg) {
                    accp[0][gg] = dot4acc(x0, wih[gg][q], accp[0][gg]);
                    accp[1][gg] = dot4acc(x1, wih[gg][q], accp[1][gg]);
                    accg[0][gg] = dot4acc(h0, whh[gg][q], accg[0][gg]);
                    accg[1][gg] = dot4acc(h1, whh[gg][q], accg[1][gg]);
                }
            }

            #pragma unroll
            for (int n = 0; n < 2; ++n)
                #pragma unroll
                for (int gg = 0; gg < 6; ++gg) {
                    const float rp = wave_red8(accp[n][gg]);
                    const float rg = wave_red8(accg[n][gg]);
                    if (kgrp == 7) { pxl[n][g0 + gg] = rp; ghl[n][g0 + gg] = rg; }
                }
            __syncthreads();

            if (tid < 256) {
                const int n = tid >> 7, j = tid & 127;
                const float pr = pxl[n][j]       + ghl[n][j]       + bsum[j];
                const float pz = pxl[n][j + 128] + ghl[n][j + 128] + bsum[j + 128];
                const float gn = ghl[n][j + 256] + bhn_[j];
                const float pn = pxl[n][j + 256] + bin_[j];
                const float r  = fsig(pr);
                const float z  = fsig(pz);
                const float nn = ftanh_(pn + r * gn);
                const int hoff = n * (8 * CH) + (j >> 4) * CH + (j & 15);
                const float hold = hb[hoff];
                const float hnew = (1.f - z) * nn + z * hold;
                hb[hoff] = hnew;
                ypend = hnew;
                have_y = true;
            } else {
                const int t2 = tid - 256;
                const int n = t2 >> 7, j = t2 & 127;
                if (s + 1 < SS && j < kin)
                    xb[(s + 1) & 1][n * (8 * CH) + (j >> 4) * CH + (j & 15)] = xpref;
            }
            __syncthreads();
        }

        if (tid < 256) {
            const int n = tid >> 7, j = tid & 127;
            yd[((SS - 1) * NB + row0 + n) * HID + j] = ypend;
        }
        __syncthreads();
    }
}

}  // namespace

extern "C" void kernel_launch(void* const* d_in, const int* in_sizes, int n_in,
                              void* d_out, int out_size, void* d_ws, size_t ws_size,
                              hipStream_t stream)
{
    (void)in_sizes; (void)n_in; (void)out_size;
    const float* xin = (const float*)d_in[0];
    const float* wih[3] = { (const float*)d_in[1], (const float*)d_in[5], (const float*)d_in[9]  };
    const float* whh[3] = { (const float*)d_in[2], (const float*)d_in[6], (const float*)d_in[10] };
    const float* bih[3] = { (const float*)d_in[3], (const float*)d_in[7], (const float*)d_in[11] };
    const float* bhh[3] = { (const float*)d_in[4], (const float*)d_in[8], (const float*)d_in[12] };
    float* out = (float*)d_out;

    const size_t need = (size_t)SS * NB * G3 * sizeof(float);  // 96 MB px buffer
    if (ws_size >= need) {
        float* px = (float*)d_ws;
        for (int l = 0; l < 3; ++l) {
            const float* A = (l == 0) ? xin : out;
            const int kin = (l == 0) ? 64 : HID;
            px_gemm<<<dim3((SS * NB) / 128, 3), dim3(256), 0, stream>>>(
                A, wih[l], bih[l], bhh[l], px, kin);
            gru_rec_mfma<<<dim3(NB / 16), dim3(NTH), 0, stream>>>(px, whh[l], bhh[l], out);
        }
    } else {
        gru3_fused<<<dim3(NB / 2), dim3(NTH), 0, stream>>>(
            xin, wih[0], whh[0], bih[0], bhh[0],
            wih[1], whh[1], bih[1], bhh[1],
            wih[2], whh[2], bih[2], bhh[2], out);
    }
}